// Round 5
// baseline (598.769 us; speedup 1.0000x reference)
//
#include <hip/hip_runtime.h>
#include <hip/hip_bf16.h>
#include <math.h>

#define N_NODES 16384
#define E_EDGES 65536
#define ET (E_EDGES + N_NODES)   /* 81920 edges incl self loops */
#define IN_DIM 1536
#define HID 1024
#define XSTR 2048                /* fused xl|xr row stride */

typedef __attribute__((ext_vector_type(8))) short bf16x8;
typedef __attribute__((ext_vector_type(4))) float f32x4;

__device__ __forceinline__ unsigned short f2b(float f) {
  unsigned int u = __float_as_uint(f);
  u = (u + 0x7FFFu + ((u >> 16) & 1u)) >> 16;
  return (unsigned short)u;
}

__device__ __forceinline__ float b2f(unsigned short u) {
  return __uint_as_float((unsigned int)u << 16);
}

__device__ __forceinline__ void gload_lds16(const void* g, void* l) {
  __builtin_amdgcn_global_load_lds((const __attribute__((address_space(1))) void*)g,
                                   (__attribute__((address_space(3))) void*)l, 16, 0, 0);
}

__device__ __forceinline__ float gelu_exact(float y) {
  return 0.5f * y * (1.0f + erff(y * 0.70710678118654752f));
}

// ---------------------------------------------------------------------------
// fp32 -> bf16 convert (vectorized)
__global__ void conv_bf16_kernel(const float* __restrict__ in, unsigned short* __restrict__ out, int n4) {
  int i = blockIdx.x * 256 + threadIdx.x;
  if (i < n4) {
    float4 v = ((const float4*)in)[i];
    ushort4 o;
    o.x = f2b(v.x); o.y = f2b(v.y); o.z = f2b(v.z); o.w = f2b(v.w);
    ((ushort4*)out)[i] = o;
  }
}

// transpose fp32 [K][N] -> bf16 [N][K]
__global__ void transpose_conv_kernel(const float* __restrict__ in, unsigned short* __restrict__ out,
                                      int K, int N) {
  __shared__ float tile[32][33];
  int bx = blockIdx.x * 32;  // n base
  int by = blockIdx.y * 32;  // k base
  int tx = threadIdx.x, ty = threadIdx.y;
  #pragma unroll
  for (int i = 0; i < 32; i += 8)
    tile[ty + i][tx] = in[(size_t)(by + ty + i) * N + bx + tx];
  __syncthreads();
  #pragma unroll
  for (int i = 0; i < 32; i += 8)
    out[(size_t)(bx + ty + i) * K + by + tx] = f2b(tile[tx][ty + i]);
}

// concat two float vectors [n] -> [2n]
__global__ void concat2_kernel(const float* __restrict__ a, const float* __restrict__ b,
                               float* __restrict__ o, int n) {
  int i = blockIdx.x * 256 + threadIdx.x;
  if (i < n) o[i] = a[i];
  else if (i < 2 * n) o[i] = b[i - n];
}

// ---------------------------------------------------------------------------
// 256x256 tile, BK=64, 512 threads (8 waves, 2x4), double-buffered LDS (128KB)
// 2-phase pipeline: stage(next) issued before compute(cur); ONE barrier/iter
// (syncthreads drains vmcnt after compute -> load latency hides under MFMA).
// Per wave: 128x64 output = 8x4 f32x4 frags, 64 MFMA per K-step.
// T2 XOR-swizzle + T1 XCD chunking as in the 128-tile kernel.
// WB: 0 fp32 only, 2 bf16 only.
template <int WB>
__global__ __launch_bounds__(512, 2)
void gemm256_kernel(const unsigned short* __restrict__ A, const unsigned short* __restrict__ Bt,
                    const float* __restrict__ bias, float* __restrict__ C,
                    unsigned short* __restrict__ Cb, int M, int N, int K, int nx) {
  __shared__ unsigned short As2[2][256 * 64];
  __shared__ unsigned short Bs2[2][256 * 64];
  const int t = threadIdx.x;
  const int l = t & 63;
  const int w = t >> 6;              // 0..7
  const int wr = w >> 2;             // 0..1  (row half: 128 rows)
  const int wc = w & 3;              // 0..3  (col quarter: 64 cols)

  // XCD-aware bijective remap (gridDim.x % 8 == 0 for all shapes here)
  const int nwg = gridDim.x;
  const int cpx = nwg >> 3;
  const int bid = blockIdx.x;
  const int tile = (bid & 7) * cpx + (bid >> 3);
  const int bm = (tile / nx) * 256;
  const int bn = (tile % nx) * 256;

  f32x4 acc[8][4];
  #pragma unroll
  for (int m = 0; m < 8; m++)
    #pragma unroll
    for (int n = 0; n < 4; n++) acc[m][n] = (f32x4){0.f, 0.f, 0.f, 0.f};

  // staging: thread t covers row srow=t>>3 (+i*64), 8 threads per 128B row;
  // source col bytes pre-swizzled by ((row&7)<<4); LDS dest linear.
  const int srow = t >> 3;                                  // 0..63
  const int scolbsw = ((t & 7) * 16) ^ ((srow & 7) << 4);   // swizzled byte col
  const unsigned short* Ag = A + (size_t)(bm + srow) * K + (scolbsw >> 1);
  const unsigned short* Bg = Bt + (size_t)(bn + srow) * K + (scolbsw >> 1);

  const int ar = wr * 128 + (l & 15);       // 0..255
  const int br = wc * 64 + (l & 15);        // 0..255
  const int kk2 = (l >> 4) * 16;            // k-fragment byte offset
  const int swA = (ar & 7) << 4;            // constant across m (m*16 % 8 == 0)
  const int swB = (br & 7) << 4;

  const int NT = K >> 6;
  int cur = 0;

  // prologue: stage K-tile 0 into buf 0, drain, barrier
  {
    char* ab = (char*)As2[0] + t * 16;
    char* bb = (char*)Bs2[0] + t * 16;
    #pragma unroll
    for (int i = 0; i < 4; i++) {
      gload_lds16(Ag + (size_t)i * 64 * K, ab + i * 8192);
      gload_lds16(Bg + (size_t)i * 64 * K, bb + i * 8192);
    }
  }
  __syncthreads();

  for (int it = 0; it < NT; ++it) {
    // issue next-tile stage into the other buffer (overlaps with compute)
    if (it + 1 < NT) {
      const int k0 = (it + 1) << 6;
      char* ab = (char*)As2[cur ^ 1] + t * 16;
      char* bb = (char*)Bs2[cur ^ 1] + t * 16;
      #pragma unroll
      for (int i = 0; i < 4; i++) {
        gload_lds16(Ag + (size_t)i * 64 * K + k0, ab + i * 8192);
        gload_lds16(Bg + (size_t)i * 64 * K + k0, bb + i * 8192);
      }
    }
    // compute current buffer
    const char* Asb = (const char*)As2[cur];
    const char* Bsb = (const char*)Bs2[cur];
    bf16x8 af[8], bfr[4];
    #pragma unroll
    for (int kh = 0; kh < 2; kh++) {
      const int kb = kk2 + kh * 64;
      #pragma unroll
      for (int m = 0; m < 8; m++)
        af[m] = *(const bf16x8*)(Asb + (ar + m * 16) * 128 + (kb ^ swA));
      #pragma unroll
      for (int n = 0; n < 4; n++)
        bfr[n] = *(const bf16x8*)(Bsb + (br + n * 16) * 128 + (kb ^ swB));
      #pragma unroll
      for (int m = 0; m < 8; m++)
        #pragma unroll
        for (int n = 0; n < 4; n++)
          acc[m][n] = __builtin_amdgcn_mfma_f32_16x16x32_bf16(af[m], bfr[n], acc[m][n], 0, 0, 0);
    }
    __syncthreads();   // drains this iter's stage (vmcnt) + read/write hazard barrier
    cur ^= 1;
  }

  const int crow0 = bm + wr * 128 + (l >> 4) * 4;
  const int ccol0 = bn + wc * 64 + (l & 15);
  #pragma unroll
  for (int m = 0; m < 8; m++) {
    #pragma unroll
    for (int n = 0; n < 4; n++) {
      int col = ccol0 + n * 16;
      float bv = bias[col];
      #pragma unroll
      for (int v = 0; v < 4; v++) {
        int row = crow0 + m * 16 + v;
        float x = acc[m][n][v] + bv;
        if (WB != 2) C[(size_t)row * N + col] = x;
        if (WB != 0) Cb[(size_t)row * N + col] = f2b(x);
      }
    }
  }
}

// ---------------------------------------------------------------------------
// bf16 MFMA GEMM (scorer path): C = A*Bt^T + bias; 256x128 tile, BK=64,
// 8 waves (4x2), single-buffer 2-barrier. ACT: 0 none, 1 silu. WB as above.
template <int ACT, int WB>
__global__ __launch_bounds__(512)
void gemm_bf16_kernel(const unsigned short* __restrict__ A, const unsigned short* __restrict__ Bt,
                      const float* __restrict__ bias, float* __restrict__ C,
                      unsigned short* __restrict__ Cb, int M, int N, int K, int nx) {
  __shared__ unsigned short As[256 * 64];
  __shared__ unsigned short Bs[128 * 64];
  const int t = threadIdx.x;
  const int l = t & 63;
  const int w = t >> 6;            // 0..7
  const int wr = w >> 1, wc = w & 1;

  const int nwg = gridDim.x;
  const int bid = blockIdx.x;
  int tile = bid;
  if ((nwg & 7) == 0) {
    const int cpx = nwg >> 3;
    tile = (bid & 7) * cpx + (bid >> 3);
  }
  const int bm = (tile / nx) * 256;
  const int bn = (tile % nx) * 128;

  f32x4 acc[4][4];
  #pragma unroll
  for (int m = 0; m < 4; m++)
    #pragma unroll
    for (int n = 0; n < 4; n++) acc[m][n] = (f32x4){0.f, 0.f, 0.f, 0.f};

  const int srow = t >> 3;                                  // 0..63
  const int scolbsw = ((t & 7) * 16) ^ ((srow & 7) << 4);   // swizzled byte col
  const unsigned short* Ag = A + (size_t)(bm + srow) * K + (scolbsw >> 1);
  const unsigned short* Bg = Bt + (size_t)(bn + srow) * K + (scolbsw >> 1);

  const int ar = wr * 64 + (l & 15);        // 0..255
  const int br = wc * 64 + (l & 15);        // 0..127
  const int kk2 = (l >> 4) * 16;            // k-fragment byte offset
  const int swA = (ar & 7) << 4;
  const int swB = (br & 7) << 4;
  const char* Asb = (const char*)As;
  const char* Bsb = (const char*)Bs;

  for (int k0 = 0; k0 < K; k0 += 64) {
    #pragma unroll
    for (int i = 0; i < 4; i++)
      gload_lds16(Ag + (size_t)i * 64 * K + k0, (char*)As + t * 16 + i * 8192);
    #pragma unroll
    for (int i = 0; i < 2; i++)
      gload_lds16(Bg + (size_t)i * 64 * K + k0, (char*)Bs + t * 16 + i * 8192);
    __syncthreads();
    bf16x8 af[4], bfr[4];
    #pragma unroll
    for (int kh = 0; kh < 2; kh++) {
      const int kb = kk2 + kh * 64;
      #pragma unroll
      for (int m = 0; m < 4; m++)
        af[m] = *(const bf16x8*)(Asb + (ar + m * 16) * 128 + (kb ^ swA));
      #pragma unroll
      for (int n = 0; n < 4; n++)
        bfr[n] = *(const bf16x8*)(Bsb + (br + n * 16) * 128 + (kb ^ swB));
      #pragma unroll
      for (int m = 0; m < 4; m++)
        #pragma unroll
        for (int n = 0; n < 4; n++)
          acc[m][n] = __builtin_amdgcn_mfma_f32_16x16x32_bf16(af[m], bfr[n], acc[m][n], 0, 0, 0);
    }
    __syncthreads();
  }

  const int crow0 = bm + wr * 64 + (l >> 4) * 4;
  const int ccol0 = bn + wc * 64 + (l & 15);
  #pragma unroll
  for (int m = 0; m < 4; m++) {
    #pragma unroll
    for (int n = 0; n < 4; n++) {
      int col = ccol0 + n * 16;
      float bv = bias[col];
      #pragma unroll
      for (int v = 0; v < 4; v++) {
        int row = crow0 + m * 16 + v;
        float x = acc[m][n][v] + bv;
        if (ACT == 1) x = x / (1.0f + expf(-x));   // silu
        if (WB != 2) C[(size_t)row * N + col] = x;
        if (WB != 0) Cb[(size_t)row * N + col] = f2b(x);
      }
    }
  }
}

// ---------------------------------------------------------------------------
// layernorm + exact gelu (+ optional residual into h); writes h fp32 and bf16
template <int RES>
__global__ __launch_bounds__(256)
void ln_gelu_kernel(const float* __restrict__ c, const float* __restrict__ g,
                    const float* __restrict__ b, float* __restrict__ h,
                    unsigned short* __restrict__ hb) {
  int row = blockIdx.x;
  int t = threadIdx.x;
  const float* cr = c + (size_t)row * HID;
  float v[4];
  float s = 0.f, q = 0.f;
  #pragma unroll
  for (int j = 0; j < 4; j++) {
    v[j] = cr[t + 256 * j];
    s += v[j];
    q += v[j] * v[j];
  }
  #pragma unroll
  for (int off = 32; off; off >>= 1) {
    s += __shfl_xor(s, off);
    q += __shfl_xor(q, off);
  }
  __shared__ float rs[4], rq[4];
  int wv = t >> 6, l = t & 63;
  if (l == 0) { rs[wv] = s; rq[wv] = q; }
  __syncthreads();
  s = rs[0] + rs[1] + rs[2] + rs[3];
  q = rq[0] + rq[1] + rq[2] + rq[3];
  float mu = s * (1.0f / HID);
  float var = q * (1.0f / HID) - mu * mu;
  float rstd = rsqrtf(var + 1e-5f);
  float* hr = h + (size_t)row * HID;
  unsigned short* hbr = hb + (size_t)row * HID;
  #pragma unroll
  for (int j = 0; j < 4; j++) {
    int ci = t + 256 * j;
    float y = (v[j] - mu) * rstd * g[ci] + b[ci];
    float z = gelu_exact(y);
    float o = RES ? (hr[ci] + z) : z;
    hr[ci] = o;
    hbr[ci] = f2b(o);
  }
}

// ---------------------------------------------------------------------------
// edge list build (+ self loops) and dst-degree histogram
__global__ void build_edges_kernel(const int* __restrict__ ei, int* __restrict__ srcA,
                                   int* __restrict__ dstA, int* __restrict__ deg) {
  int i = blockIdx.x * 256 + threadIdx.x;
  if (i >= ET) return;
  int s, d;
  if (i < E_EDGES) { s = ei[i]; d = ei[E_EDGES + i]; }
  else             { s = i - E_EDGES; d = s; }
  srcA[i] = s;
  dstA[i] = d;
  atomicAdd(&deg[d], 1);
}

// exclusive scan of 16384 degrees, single block of 1024 threads
__global__ __launch_bounds__(1024)
void scan16k_kernel(const int* __restrict__ deg, int* __restrict__ rowstart) {
  __shared__ int s[1024];
  int t = threadIdx.x;
  int local[16];
  int sum = 0;
  #pragma unroll
  for (int i = 0; i < 16; i++) { local[i] = deg[t * 16 + i]; sum += local[i]; }
  s[t] = sum;
  __syncthreads();
  for (int off = 1; off < 1024; off <<= 1) {
    int v = (t >= off) ? s[t - off] : 0;
    __syncthreads();
    s[t] += v;
    __syncthreads();
  }
  int run = s[t] - sum;
  #pragma unroll
  for (int i = 0; i < 16; i++) { rowstart[t * 16 + i] = run; run += local[i]; }
  if (t == 1023) rowstart[16384] = run;
}

// scatter edges into CSR slots; store src and dst per CSR position
__global__ void scatter_edges_kernel(const int* __restrict__ srcA, const int* __restrict__ dstA,
                                     const int* __restrict__ rowstart, int* __restrict__ cursor,
                                     int* __restrict__ src_csr, int* __restrict__ dst_csr) {
  int i = blockIdx.x * 256 + threadIdx.x;
  if (i >= ET) return;
  int d = dstA[i];
  int pos = atomicAdd(&cursor[d], 1);
  int p = rowstart[d] + pos;
  src_csr[p] = srcA[i];
  dst_csr[p] = d;
}

// ---------------------------------------------------------------------------
// per-edge attention logits over CSR order (consecutive waves share dst row).
// xe = fused [N][2048] bf16: cols 0..1023 = xl, 1024..2047 = xr.
__global__ __launch_bounds__(256)
void edge_logits_kernel(const unsigned short* __restrict__ xe,
                        const float* __restrict__ att, const int* __restrict__ src_csr,
                        const int* __restrict__ dst_csr, float* __restrict__ logits) {
  int e = blockIdx.x * 4 + (threadIdx.x >> 6);
  int l = threadIdx.x & 63;
  int s = src_csr[e], d = dst_csr[e];
  const unsigned short* xls = xe + (size_t)s * XSTR + l * 16;
  const unsigned short* xrd = xe + (size_t)d * XSTR + 1024 + l * 16;
  bf16x8 a0 = *(const bf16x8*)xls;
  bf16x8 a1 = *(const bf16x8*)(xls + 8);
  bf16x8 b0 = *(const bf16x8*)xrd;
  bf16x8 b1 = *(const bf16x8*)(xrd + 8);
  const float* ac = att + l * 16;
  float p = 0.f;
  #pragma unroll
  for (int j = 0; j < 8; j++) {
    float u = b2f((unsigned short)a0[j]) + b2f((unsigned short)b0[j]);
    float v = b2f((unsigned short)a1[j]) + b2f((unsigned short)b1[j]);
    u = u > 0.f ? u : 0.2f * u;
    v = v > 0.f ? v : 0.2f * v;
    p += u * ac[j] + v * ac[j + 8];
  }
  p += __shfl_xor(p, 1);
  p += __shfl_xor(p, 2);
  p += __shfl_xor(p, 4);
  if ((l & 7) == 0) logits[(size_t)e * 8 + (l >> 3)] = p;
}

// per-(node,head) softmax over CSR-contiguous logits -> alpha
__global__ __launch_bounds__(256)
void alpha_kernel(const float* __restrict__ logits, const int* __restrict__ rowstart,
                  float* __restrict__ alpha) {
  int gid = blockIdx.x * 256 + threadIdx.x;
  if (gid >= N_NODES * 8) return;
  int nid = gid >> 3, hh = gid & 7;
  int beg = rowstart[nid], end = rowstart[nid + 1];
  float m = -1e30f;
  for (int i = beg; i < end; i++) m = fmaxf(m, logits[(size_t)i * 8 + hh]);
  float den = 0.f;
  for (int i = beg; i < end; i++) den += expf(logits[(size_t)i * 8 + hh] - m);
  float inv = 1.0f / den;
  for (int i = beg; i < end; i++) alpha[(size_t)i * 8 + hh] = expf(logits[(size_t)i * 8 + hh] - m) * inv;
}

// per-dst aggregate: out[n] = sum_e alpha[e]*xl[src_e] + bo   (bf16 gathers)
__global__ __launch_bounds__(256)
void gat_aggregate_kernel(const unsigned short* __restrict__ xe, const float* __restrict__ alpha,
                          const int* __restrict__ src_csr, const int* __restrict__ rowstart,
                          const float* __restrict__ bo, float* __restrict__ out) {
  int nid = blockIdx.x;
  int beg = rowstart[nid], end = rowstart[nid + 1];
  int t = threadIdx.x;
  int c0 = t * 4;
  int hh = t >> 5;          // c0>>7
  float acc0 = 0.f, acc1 = 0.f, acc2 = 0.f, acc3 = 0.f;
  for (int i = beg; i < end; i++) {
    float a = alpha[(size_t)i * 8 + hh];
    int s = src_csr[i];
    ushort4 v = *(const ushort4*)(xe + (size_t)s * XSTR + c0);
    acc0 += a * b2f(v.x);
    acc1 += a * b2f(v.y);
    acc2 += a * b2f(v.z);
    acc3 += a * b2f(v.w);
  }
  const float4 bv = *(const float4*)(bo + c0);
  float4 o;
  o.x = acc0 + bv.x; o.y = acc1 + bv.y; o.z = acc2 + bv.z; o.w = acc3 + bv.w;
  *(float4*)(out + (size_t)nid * HID + c0) = o;
}

// final scorer dot: scores[n] = dot(s2[n][0:128], Ws3) + bs3
__global__ __launch_bounds__(256)
void score_kernel(const float* __restrict__ s2, const float* __restrict__ Ws3,
                  const float* __restrict__ bs3, float* __restrict__ out) {
  int nid = blockIdx.x * 4 + (threadIdx.x >> 6);
  int l = threadIdx.x & 63;
  const float* r = s2 + (size_t)nid * 128;
  float a = r[l] * Ws3[l] + r[l + 64] * Ws3[l + 64];
  #pragma unroll
  for (int off = 32; off; off >>= 1) a += __shfl_xor(a, off);
  if (l == 0) out[nid] = a + bs3[0];
}

// ---------------------------------------------------------------------------
extern "C" void kernel_launch(void* const* d_in, const int* in_sizes, int n_in,
                              void* d_out, int out_size, void* d_ws, size_t ws_size,
                              hipStream_t stream) {
  const float* x    = (const float*)d_in[0];
  const int*   ei   = (const int*)  d_in[1];
  const float* W_in = (const float*)d_in[2];
  const float* b_in = (const float*)d_in[3];
  const float* ln1g = (const float*)d_in[4];
  const float* ln1b = (const float*)d_in[5];
  const float* g1Wl = (const float*)d_in[6];
  const float* g1bl = (const float*)d_in[7];
  const float* g1Wr = (const float*)d_in[8];
  const float* g1br = (const float*)d_in[9];
  const float* g1att= (const float*)d_in[10];
  const float* g1bo = (const float*)d_in[11];
  const float* ln2g = (const float*)d_in[12];
  const float* ln2b = (const float*)d_in[13];
  const float* g2Wl = (const float*)d_in[14];
  const float* g2bl = (const float*)d_in[15];
  const float* g2Wr = (const float*)d_in[16];
  const float* g2br = (const float*)d_in[17];
  const float* g2att= (const float*)d_in[18];
  const float* g2bo = (const float*)d_in[19];
  const float* ln3g = (const float*)d_in[20];
  const float* ln3b = (const float*)d_in[21];
  const float* Ws1  = (const float*)d_in[22];
  const float* bs1  = (const float*)d_in[23];
  const float* Ws2  = (const float*)d_in[24];
  const float* bs2  = (const float*)d_in[25];
  const float* Ws3  = (const float*)d_in[26];
  const float* bs3  = (const float*)d_in[27];

  float* scores = (float*)d_out;
  float* h      = (float*)d_out + N_NODES;  // [N][1024] fp32, second output

  char* wsp = (char*)d_ws;
  size_t off = 0;
  auto alloc = [&](size_t bytes) -> char* {
    char* p = wsp + off;
    off += (bytes + 255) & ~(size_t)255;
    return p;
  };
  unsigned short* xb    = (unsigned short*)alloc((size_t)N_NODES * IN_DIM * 2);
  unsigned short* WinT  = (unsigned short*)alloc((size_t)HID * IN_DIM * 2);
  unsigned short* g1WT  = (unsigned short*)alloc((size_t)XSTR * HID * 2);  // [Wl;Wr]^T
  unsigned short* g2WT  = (unsigned short*)alloc((size_t)XSTR * HID * 2);
  unsigned short* Ws1T  = (unsigned short*)alloc((size_t)512 * HID * 2);
  unsigned short* Ws2T  = (unsigned short*)alloc((size_t)128 * 512 * 2);
  unsigned short* hb    = (unsigned short*)alloc((size_t)N_NODES * HID * 2);
  unsigned short* s1b   = (unsigned short*)alloc((size_t)N_NODES * 512 * 2);
  unsigned short* xe    = (unsigned short*)alloc((size_t)N_NODES * XSTR * 2); // fused xl|xr
  float* bcat1  = (float*)alloc((size_t)XSTR * 4);
  float* bcat2  = (float*)alloc((size_t)XSTR * 4);
  float* C      = (float*)alloc((size_t)N_NODES * HID * 4);
  float* logits = (float*)alloc((size_t)ET * 8 * 4);
  float* alpha  = (float*)alloc((size_t)ET * 8 * 4);
  int* srcA     = (int*)alloc((size_t)ET * 4);
  int* dstA     = (int*)alloc((size_t)ET * 4);
  int* deg      = (int*)alloc(65536);
  int* cursor   = (int*)alloc(65536);
  int* rowstart = (int*)alloc(65544);
  int* src_csr  = (int*)alloc((size_t)ET * 4);
  int* dst_csr  = (int*)alloc((size_t)ET * 4);

  // --- weight/input conversions ---
  conv_bf16_kernel<<<(N_NODES * IN_DIM / 4 + 255) / 256, 256, 0, stream>>>(x, xb, N_NODES * IN_DIM / 4);
  dim3 tb(32, 8);
  transpose_conv_kernel<<<dim3(HID / 32, IN_DIM / 32), tb, 0, stream>>>(W_in, WinT, IN_DIM, HID);
  transpose_conv_kernel<<<dim3(HID / 32, HID / 32), tb, 0, stream>>>(g1Wl, g1WT, HID, HID);
  transpose_conv_kernel<<<dim3(HID / 32, HID / 32), tb, 0, stream>>>(g1Wr, g1WT + (size_t)HID * HID, HID, HID);
  transpose_conv_kernel<<<dim3(HID / 32, HID / 32), tb, 0, stream>>>(g2Wl, g2WT, HID, HID);
  transpose_conv_kernel<<<dim3(HID / 32, HID / 32), tb, 0, stream>>>(g2Wr, g2WT + (size_t)HID * HID, HID, HID);
  transpose_conv_kernel<<<dim3(512 / 32, HID / 32), tb, 0, stream>>>(Ws1, Ws1T, HID, 512);
  transpose_conv_kernel<<<dim3(128 / 32, 512 / 32), tb, 0, stream>>>(Ws2, Ws2T, 512, 128);
  concat2_kernel<<<XSTR / 256, 256, 0, stream>>>(g1bl, g1br, bcat1, HID);
  concat2_kernel<<<XSTR / 256, 256, 0, stream>>>(g2bl, g2br, bcat2, HID);

  // --- CSR build (shared by both GAT layers) ---
  hipMemsetAsync(deg, 0, 131072, stream);  // deg + cursor (contiguous)
  build_edges_kernel<<<ET / 256, 256, 0, stream>>>(ei, srcA, dstA, deg);
  scan16k_kernel<<<1, 1024, 0, stream>>>(deg, rowstart);
  scatter_edges_kernel<<<ET / 256, 256, 0, stream>>>(srcA, dstA, rowstart, cursor, src_csr, dst_csr);

  // --- input projection + LN1 + gelu ---
  gemm256_kernel<0><<<(N_NODES / 256) * (HID / 256), 512, 0, stream>>>(
      xb, WinT, b_in, C, nullptr, N_NODES, HID, IN_DIM, HID / 256);
  ln_gelu_kernel<0><<<N_NODES, 256, 0, stream>>>(C, ln1g, ln1b, h, hb);

  // --- GAT layer 1 (fused xl|xr projection, N=2048) ---
  gemm256_kernel<2><<<(N_NODES / 256) * (XSTR / 256), 512, 0, stream>>>(
      hb, g1WT, bcat1, nullptr, xe, N_NODES, XSTR, HID, XSTR / 256);
  edge_logits_kernel<<<ET / 4, 256, 0, stream>>>(xe, g1att, src_csr, dst_csr, logits);
  alpha_kernel<<<N_NODES * 8 / 256, 256, 0, stream>>>(logits, rowstart, alpha);
  gat_aggregate_kernel<<<N_NODES, 256, 0, stream>>>(xe, alpha, src_csr, rowstart, g1bo, C);
  ln_gelu_kernel<1><<<N_NODES, 256, 0, stream>>>(C, ln2g, ln2b, h, hb);

  // --- GAT layer 2 ---
  gemm256_kernel<2><<<(N_NODES / 256) * (XSTR / 256), 512, 0, stream>>>(
      hb, g2WT, bcat2, nullptr, xe, N_NODES, XSTR, HID, XSTR / 256);
  edge_logits_kernel<<<ET / 4, 256, 0, stream>>>(xe, g2att, src_csr, dst_csr, logits);
  alpha_kernel<<<N_NODES * 8 / 256, 256, 0, stream>>>(logits, rowstart, alpha);
  gat_aggregate_kernel<<<N_NODES, 256, 0, stream>>>(xe, alpha, src_csr, rowstart, g2bo, C);
  ln_gelu_kernel<1><<<N_NODES, 256, 0, stream>>>(C, ln3g, ln3b, h, hb);

  // --- scorer MLP ---
  gemm_bf16_kernel<1, 2><<<(N_NODES / 256) * (512 / 128), 512, 0, stream>>>(
      hb, Ws1T, bs1, nullptr, s1b, N_NODES, 512, HID, 512 / 128);
  gemm_bf16_kernel<1, 0><<<(N_NODES / 256) * 1, 512, 0, stream>>>(
      s1b, Ws2T, bs2, C, nullptr, N_NODES, 128, 512, 1);
  score_kernel<<<N_NODES / 4, 256, 0, stream>>>(C, Ws3, bs3, scores);
}

// Round 6
// 568.288 us; speedup vs baseline: 1.0536x; 1.0536x over previous
//
#include <hip/hip_runtime.h>
#include <hip/hip_bf16.h>
#include <math.h>

#define N_NODES 16384
#define E_EDGES 65536
#define ET (E_EDGES + N_NODES)   /* 81920 edges incl self loops */
#define IN_DIM 1536
#define HID 1024
#define XSTR 2048                /* fused xl|xr row stride */

typedef __attribute__((ext_vector_type(8))) short bf16x8;
typedef __attribute__((ext_vector_type(4))) float f32x4;

__device__ __forceinline__ unsigned short f2b(float f) {
  unsigned int u = __float_as_uint(f);
  u = (u + 0x7FFFu + ((u >> 16) & 1u)) >> 16;
  return (unsigned short)u;
}

__device__ __forceinline__ float b2f(unsigned short u) {
  return __uint_as_float((unsigned int)u << 16);
}

__device__ __forceinline__ void gload_lds16(const void* g, void* l) {
  __builtin_amdgcn_global_load_lds((const __attribute__((address_space(1))) void*)g,
                                   (__attribute__((address_space(3))) void*)l, 16, 0, 0);
}

__device__ __forceinline__ float gelu_exact(float y) {
  return 0.5f * y * (1.0f + erff(y * 0.70710678118654752f));
}

// ---------------------------------------------------------------------------
// fp32 -> bf16 convert (vectorized)
__global__ void conv_bf16_kernel(const float* __restrict__ in, unsigned short* __restrict__ out, int n4) {
  int i = blockIdx.x * 256 + threadIdx.x;
  if (i < n4) {
    float4 v = ((const float4*)in)[i];
    ushort4 o;
    o.x = f2b(v.x); o.y = f2b(v.y); o.z = f2b(v.z); o.w = f2b(v.w);
    ((ushort4*)out)[i] = o;
  }
}

// transpose fp32 [K][N] -> bf16 [N][K]
__global__ void transpose_conv_kernel(const float* __restrict__ in, unsigned short* __restrict__ out,
                                      int K, int N) {
  __shared__ float tile[32][33];
  int bx = blockIdx.x * 32;  // n base
  int by = blockIdx.y * 32;  // k base
  int tx = threadIdx.x, ty = threadIdx.y;
  #pragma unroll
  for (int i = 0; i < 32; i += 8)
    tile[ty + i][tx] = in[(size_t)(by + ty + i) * N + bx + tx];
  __syncthreads();
  #pragma unroll
  for (int i = 0; i < 32; i += 8)
    out[(size_t)(bx + ty + i) * K + by + tx] = f2b(tile[tx][ty + i]);
}

// concat two float vectors [n] -> [2n]
__global__ void concat2_kernel(const float* __restrict__ a, const float* __restrict__ b,
                               float* __restrict__ o, int n) {
  int i = blockIdx.x * 256 + threadIdx.x;
  if (i < n) o[i] = a[i];
  else if (i < 2 * n) o[i] = b[i - n];
}

// ---------------------------------------------------------------------------
// bf16 MFMA GEMM: C = A*Bt^T + bias; 256x128 tile, BK=64, 8 waves (4x2),
// single-buffer 2-barrier (proven 902 TF structure; 48KB LDS -> 3 blocks/CU,
// cross-block wave overlap hides the barrier drain).
// T2 XOR-swizzle (byte ^= (row&7)<<4) via pre-swizzled global source + T1 XCD
// chunking. ACT: 0 none, 1 silu.  WB: 0 fp32 only, 2 bf16 only.
template <int ACT, int WB>
__global__ __launch_bounds__(512)
void gemm_bf16_kernel(const unsigned short* __restrict__ A, const unsigned short* __restrict__ Bt,
                      const float* __restrict__ bias, float* __restrict__ C,
                      unsigned short* __restrict__ Cb, int M, int N, int K, int nx) {
  __shared__ unsigned short As[256 * 64];
  __shared__ unsigned short Bs[128 * 64];
  const int t = threadIdx.x;
  const int l = t & 63;
  const int w = t >> 6;            // 0..7
  const int wr = w >> 1, wc = w & 1;

  const int nwg = gridDim.x;
  const int bid = blockIdx.x;
  int tile = bid;
  if ((nwg & 7) == 0) {
    const int cpx = nwg >> 3;
    tile = (bid & 7) * cpx + (bid >> 3);
  }
  const int bm = (tile / nx) * 256;
  const int bn = (tile % nx) * 128;

  f32x4 acc[4][4];
  #pragma unroll
  for (int m = 0; m < 4; m++)
    #pragma unroll
    for (int n = 0; n < 4; n++) acc[m][n] = (f32x4){0.f, 0.f, 0.f, 0.f};

  const int srow = t >> 3;                                  // 0..63
  const int scolbsw = ((t & 7) * 16) ^ ((srow & 7) << 4);   // swizzled byte col
  const unsigned short* Ag = A + (size_t)(bm + srow) * K + (scolbsw >> 1);
  const unsigned short* Bg = Bt + (size_t)(bn + srow) * K + (scolbsw >> 1);

  const int ar = wr * 64 + (l & 15);        // 0..255
  const int br = wc * 64 + (l & 15);        // 0..127
  const int kk2 = (l >> 4) * 16;            // k-fragment byte offset
  const int swA = (ar & 7) << 4;
  const int swB = (br & 7) << 4;
  const char* Asb = (const char*)As;
  const char* Bsb = (const char*)Bs;

  for (int k0 = 0; k0 < K; k0 += 64) {
    #pragma unroll
    for (int i = 0; i < 4; i++)
      gload_lds16(Ag + (size_t)i * 64 * K + k0, (char*)As + t * 16 + i * 8192);
    #pragma unroll
    for (int i = 0; i < 2; i++)
      gload_lds16(Bg + (size_t)i * 64 * K + k0, (char*)Bs + t * 16 + i * 8192);
    __syncthreads();
    bf16x8 af[4], bfr[4];
    #pragma unroll
    for (int kh = 0; kh < 2; kh++) {
      const int kb = kk2 + kh * 64;
      #pragma unroll
      for (int m = 0; m < 4; m++)
        af[m] = *(const bf16x8*)(Asb + (ar + m * 16) * 128 + (kb ^ swA));
      #pragma unroll
      for (int n = 0; n < 4; n++)
        bfr[n] = *(const bf16x8*)(Bsb + (br + n * 16) * 128 + (kb ^ swB));
      #pragma unroll
      for (int m = 0; m < 4; m++)
        #pragma unroll
        for (int n = 0; n < 4; n++)
          acc[m][n] = __builtin_amdgcn_mfma_f32_16x16x32_bf16(af[m], bfr[n], acc[m][n], 0, 0, 0);
    }
    __syncthreads();
  }

  const int crow0 = bm + wr * 64 + (l >> 4) * 4;
  const int ccol0 = bn + wc * 64 + (l & 15);
  #pragma unroll
  for (int m = 0; m < 4; m++) {
    #pragma unroll
    for (int n = 0; n < 4; n++) {
      int col = ccol0 + n * 16;
      float bv = bias[col];
      #pragma unroll
      for (int v = 0; v < 4; v++) {
        int row = crow0 + m * 16 + v;
        float x = acc[m][n][v] + bv;
        if (ACT == 1) x = x / (1.0f + expf(-x));   // silu
        if (WB != 2) C[(size_t)row * N + col] = x;
        if (WB != 0) Cb[(size_t)row * N + col] = f2b(x);
      }
    }
  }
}

// ---------------------------------------------------------------------------
// layernorm + exact gelu (no residual; used after input projection only)
__global__ __launch_bounds__(256)
void ln_gelu_kernel(const float* __restrict__ c, const float* __restrict__ g,
                    const float* __restrict__ b, float* __restrict__ h,
                    unsigned short* __restrict__ hb) {
  int row = blockIdx.x;
  int t = threadIdx.x;
  const float* cr = c + (size_t)row * HID;
  float v[4];
  float s = 0.f, q = 0.f;
  #pragma unroll
  for (int j = 0; j < 4; j++) {
    v[j] = cr[t + 256 * j];
    s += v[j];
    q += v[j] * v[j];
  }
  #pragma unroll
  for (int off = 32; off; off >>= 1) {
    s += __shfl_xor(s, off);
    q += __shfl_xor(q, off);
  }
  __shared__ float rs[4], rq[4];
  int wv = t >> 6, l = t & 63;
  if (l == 0) { rs[wv] = s; rq[wv] = q; }
  __syncthreads();
  s = rs[0] + rs[1] + rs[2] + rs[3];
  q = rq[0] + rq[1] + rq[2] + rq[3];
  float mu = s * (1.0f / HID);
  float var = q * (1.0f / HID) - mu * mu;
  float rstd = rsqrtf(var + 1e-5f);
  float* hr = h + (size_t)row * HID;
  unsigned short* hbr = hb + (size_t)row * HID;
  #pragma unroll
  for (int j = 0; j < 4; j++) {
    int ci = t + 256 * j;
    float y = (v[j] - mu) * rstd * g[ci] + b[ci];
    float z = gelu_exact(y);
    hr[ci] = z;
    hbr[ci] = f2b(z);
  }
}

// ---------------------------------------------------------------------------
// edge list build (+ self loops) and dst-degree histogram
__global__ void build_edges_kernel(const int* __restrict__ ei, int* __restrict__ srcA,
                                   int* __restrict__ dstA, int* __restrict__ deg) {
  int i = blockIdx.x * 256 + threadIdx.x;
  if (i >= ET) return;
  int s, d;
  if (i < E_EDGES) { s = ei[i]; d = ei[E_EDGES + i]; }
  else             { s = i - E_EDGES; d = s; }
  srcA[i] = s;
  dstA[i] = d;
  atomicAdd(&deg[d], 1);
}

// exclusive scan of 16384 degrees, single block of 1024 threads
__global__ __launch_bounds__(1024)
void scan16k_kernel(const int* __restrict__ deg, int* __restrict__ rowstart) {
  __shared__ int s[1024];
  int t = threadIdx.x;
  int local[16];
  int sum = 0;
  #pragma unroll
  for (int i = 0; i < 16; i++) { local[i] = deg[t * 16 + i]; sum += local[i]; }
  s[t] = sum;
  __syncthreads();
  for (int off = 1; off < 1024; off <<= 1) {
    int v = (t >= off) ? s[t - off] : 0;
    __syncthreads();
    s[t] += v;
    __syncthreads();
  }
  int run = s[t] - sum;
  #pragma unroll
  for (int i = 0; i < 16; i++) { rowstart[t * 16 + i] = run; run += local[i]; }
  if (t == 1023) rowstart[16384] = run;
}

// scatter edges into CSR slots; store src and dst per CSR position
__global__ void scatter_edges_kernel(const int* __restrict__ srcA, const int* __restrict__ dstA,
                                     const int* __restrict__ rowstart, int* __restrict__ cursor,
                                     int* __restrict__ src_csr, int* __restrict__ dst_csr) {
  int i = blockIdx.x * 256 + threadIdx.x;
  if (i >= ET) return;
  int d = dstA[i];
  int pos = atomicAdd(&cursor[d], 1);
  int p = rowstart[d] + pos;
  src_csr[p] = srcA[i];
  dst_csr[p] = d;
}

// ---------------------------------------------------------------------------
// per-edge attention logits over CSR order (consecutive waves share dst row).
// xe = fused [N][2048] bf16: cols 0..1023 = xl, 1024..2047 = xr.
__global__ __launch_bounds__(256)
void edge_logits_kernel(const unsigned short* __restrict__ xe,
                        const float* __restrict__ att, const int* __restrict__ src_csr,
                        const int* __restrict__ dst_csr, float* __restrict__ logits) {
  int e = blockIdx.x * 4 + (threadIdx.x >> 6);
  int l = threadIdx.x & 63;
  int s = src_csr[e], d = dst_csr[e];
  const unsigned short* xls = xe + (size_t)s * XSTR + l * 16;
  const unsigned short* xrd = xe + (size_t)d * XSTR + 1024 + l * 16;
  bf16x8 a0 = *(const bf16x8*)xls;
  bf16x8 a1 = *(const bf16x8*)(xls + 8);
  bf16x8 b0 = *(const bf16x8*)xrd;
  bf16x8 b1 = *(const bf16x8*)(xrd + 8);
  const float* ac = att + l * 16;
  float p = 0.f;
  #pragma unroll
  for (int j = 0; j < 8; j++) {
    float u = b2f((unsigned short)a0[j]) + b2f((unsigned short)b0[j]);
    float v = b2f((unsigned short)a1[j]) + b2f((unsigned short)b1[j]);
    u = u > 0.f ? u : 0.2f * u;
    v = v > 0.f ? v : 0.2f * v;
    p += u * ac[j] + v * ac[j + 8];
  }
  p += __shfl_xor(p, 1);
  p += __shfl_xor(p, 2);
  p += __shfl_xor(p, 4);
  if ((l & 7) == 0) logits[(size_t)e * 8 + (l >> 3)] = p;
}

// ---------------------------------------------------------------------------
// FUSED: per-node softmax(alpha) + aggregate + bias + LayerNorm + gelu +
// residual. One block (256 thr) per node; thread t owns channels [4t,4t+4).
// Removes the fp32 C round-trip (134 MB/layer) and the alpha pass.
__global__ __launch_bounds__(256)
void gat_agg_ln_kernel(const unsigned short* __restrict__ xe, const float* __restrict__ logits,
                       const int* __restrict__ src_csr, const int* __restrict__ rowstart,
                       const float* __restrict__ bo, const float* __restrict__ lng,
                       const float* __restrict__ lnb, float* __restrict__ h,
                       unsigned short* __restrict__ hb) {
  int nid = blockIdx.x;
  int beg = rowstart[nid], end = rowstart[nid + 1];
  int t = threadIdx.x;
  int c0 = t * 4;
  int hh = t >> 5;          // head = c0>>7
  // softmax stats for this head (32 threads of same hh compute redundantly;
  // logits reads are L1-broadcast, exp is cheap VALU)
  float m = -1e30f;
  for (int i = beg; i < end; i++) m = fmaxf(m, logits[(size_t)i * 8 + hh]);
  float den = 0.f;
  for (int i = beg; i < end; i++) den += expf(logits[(size_t)i * 8 + hh] - m);
  float inv = 1.0f / den;
  // weighted aggregate of xl rows (bf16 gather, 2KB/edge coalesced)
  float a0 = 0.f, a1 = 0.f, a2 = 0.f, a3 = 0.f;
  for (int i = beg; i < end; i++) {
    float a = expf(logits[(size_t)i * 8 + hh] - m) * inv;
    int s = src_csr[i];
    ushort4 v = *(const ushort4*)(xe + (size_t)s * XSTR + c0);
    a0 += a * b2f(v.x);
    a1 += a * b2f(v.y);
    a2 += a * b2f(v.z);
    a3 += a * b2f(v.w);
  }
  const float4 bv = *(const float4*)(bo + c0);
  float v0 = a0 + bv.x, v1 = a1 + bv.y, v2 = a2 + bv.z, v3 = a3 + bv.w;
  // block-wide LN reduction over the 1024-channel row
  float s = v0 + v1 + v2 + v3;
  float q = v0 * v0 + v1 * v1 + v2 * v2 + v3 * v3;
  #pragma unroll
  for (int off = 32; off; off >>= 1) {
    s += __shfl_xor(s, off);
    q += __shfl_xor(q, off);
  }
  __shared__ float rs[4], rq[4];
  int wv = t >> 6, l = t & 63;
  if (l == 0) { rs[wv] = s; rq[wv] = q; }
  __syncthreads();
  s = rs[0] + rs[1] + rs[2] + rs[3];
  q = rq[0] + rq[1] + rq[2] + rq[3];
  float mu = s * (1.0f / HID);
  float var = q * (1.0f / HID) - mu * mu;
  float rstd = rsqrtf(var + 1e-5f);
  const float4 gv = *(const float4*)(lng + c0);
  const float4 bbv = *(const float4*)(lnb + c0);
  float* hr = h + (size_t)nid * HID;
  float4 hold = *(const float4*)(hr + c0);
  float o0 = hold.x + gelu_exact((v0 - mu) * rstd * gv.x + bbv.x);
  float o1 = hold.y + gelu_exact((v1 - mu) * rstd * gv.y + bbv.y);
  float o2 = hold.z + gelu_exact((v2 - mu) * rstd * gv.z + bbv.z);
  float o3 = hold.w + gelu_exact((v3 - mu) * rstd * gv.w + bbv.w);
  *(float4*)(hr + c0) = (float4){o0, o1, o2, o3};
  ushort4 ob;
  ob.x = f2b(o0); ob.y = f2b(o1); ob.z = f2b(o2); ob.w = f2b(o3);
  *(ushort4*)(hb + (size_t)nid * HID + c0) = ob;
}

// final scorer dot: scores[n] = dot(s2[n][0:128], Ws3) + bs3
__global__ __launch_bounds__(256)
void score_kernel(const float* __restrict__ s2, const float* __restrict__ Ws3,
                  const float* __restrict__ bs3, float* __restrict__ out) {
  int nid = blockIdx.x * 4 + (threadIdx.x >> 6);
  int l = threadIdx.x & 63;
  const float* r = s2 + (size_t)nid * 128;
  float a = r[l] * Ws3[l] + r[l + 64] * Ws3[l + 64];
  #pragma unroll
  for (int off = 32; off; off >>= 1) a += __shfl_xor(a, off);
  if (l == 0) out[nid] = a + bs3[0];
}

// ---------------------------------------------------------------------------
extern "C" void kernel_launch(void* const* d_in, const int* in_sizes, int n_in,
                              void* d_out, int out_size, void* d_ws, size_t ws_size,
                              hipStream_t stream) {
  const float* x    = (const float*)d_in[0];
  const int*   ei   = (const int*)  d_in[1];
  const float* W_in = (const float*)d_in[2];
  const float* b_in = (const float*)d_in[3];
  const float* ln1g = (const float*)d_in[4];
  const float* ln1b = (const float*)d_in[5];
  const float* g1Wl = (const float*)d_in[6];
  const float* g1bl = (const float*)d_in[7];
  const float* g1Wr = (const float*)d_in[8];
  const float* g1br = (const float*)d_in[9];
  const float* g1att= (const float*)d_in[10];
  const float* g1bo = (const float*)d_in[11];
  const float* ln2g = (const float*)d_in[12];
  const float* ln2b = (const float*)d_in[13];
  const float* g2Wl = (const float*)d_in[14];
  const float* g2bl = (const float*)d_in[15];
  const float* g2Wr = (const float*)d_in[16];
  const float* g2br = (const float*)d_in[17];
  const float* g2att= (const float*)d_in[18];
  const float* g2bo = (const float*)d_in[19];
  const float* ln3g = (const float*)d_in[20];
  const float* ln3b = (const float*)d_in[21];
  const float* Ws1  = (const float*)d_in[22];
  const float* bs1  = (const float*)d_in[23];
  const float* Ws2  = (const float*)d_in[24];
  const float* bs2  = (const float*)d_in[25];
  const float* Ws3  = (const float*)d_in[26];
  const float* bs3  = (const float*)d_in[27];

  float* scores = (float*)d_out;
  float* h      = (float*)d_out + N_NODES;  // [N][1024] fp32, second output

  char* wsp = (char*)d_ws;
  size_t off = 0;
  auto alloc = [&](size_t bytes) -> char* {
    char* p = wsp + off;
    off += (bytes + 255) & ~(size_t)255;
    return p;
  };
  unsigned short* xb    = (unsigned short*)alloc((size_t)N_NODES * IN_DIM * 2);
  unsigned short* WinT  = (unsigned short*)alloc((size_t)HID * IN_DIM * 2);
  unsigned short* g1WT  = (unsigned short*)alloc((size_t)XSTR * HID * 2);  // [Wl;Wr]^T
  unsigned short* g2WT  = (unsigned short*)alloc((size_t)XSTR * HID * 2);
  unsigned short* Ws1T  = (unsigned short*)alloc((size_t)512 * HID * 2);
  unsigned short* Ws2T  = (unsigned short*)alloc((size_t)128 * 512 * 2);
  unsigned short* hb    = (unsigned short*)alloc((size_t)N_NODES * HID * 2);
  unsigned short* s1b   = (unsigned short*)alloc((size_t)N_NODES * 512 * 2);
  unsigned short* xe    = (unsigned short*)alloc((size_t)N_NODES * XSTR * 2); // fused xl|xr
  float* bcat1  = (float*)alloc((size_t)XSTR * 4);
  float* bcat2  = (float*)alloc((size_t)XSTR * 4);
  float* C      = (float*)alloc((size_t)N_NODES * HID * 4);
  float* logits = (float*)alloc((size_t)ET * 8 * 4);
  int* srcA     = (int*)alloc((size_t)ET * 4);
  int* dstA     = (int*)alloc((size_t)ET * 4);
  int* deg      = (int*)alloc(65536);
  int* cursor   = (int*)alloc(65536);
  int* rowstart = (int*)alloc(65544);
  int* src_csr  = (int*)alloc((size_t)ET * 4);
  int* dst_csr  = (int*)alloc((size_t)ET * 4);

  // --- weight/input conversions ---
  conv_bf16_kernel<<<(N_NODES * IN_DIM / 4 + 255) / 256, 256, 0, stream>>>(x, xb, N_NODES * IN_DIM / 4);
  dim3 tb(32, 8);
  transpose_conv_kernel<<<dim3(HID / 32, IN_DIM / 32), tb, 0, stream>>>(W_in, WinT, IN_DIM, HID);
  transpose_conv_kernel<<<dim3(HID / 32, HID / 32), tb, 0, stream>>>(g1Wl, g1WT, HID, HID);
  transpose_conv_kernel<<<dim3(HID / 32, HID / 32), tb, 0, stream>>>(g1Wr, g1WT + (size_t)HID * HID, HID, HID);
  transpose_conv_kernel<<<dim3(HID / 32, HID / 32), tb, 0, stream>>>(g2Wl, g2WT, HID, HID);
  transpose_conv_kernel<<<dim3(HID / 32, HID / 32), tb, 0, stream>>>(g2Wr, g2WT + (size_t)HID * HID, HID, HID);
  transpose_conv_kernel<<<dim3(512 / 32, HID / 32), tb, 0, stream>>>(Ws1, Ws1T, HID, 512);
  transpose_conv_kernel<<<dim3(128 / 32, 512 / 32), tb, 0, stream>>>(Ws2, Ws2T, 512, 128);
  concat2_kernel<<<XSTR / 256, 256, 0, stream>>>(g1bl, g1br, bcat1, HID);
  concat2_kernel<<<XSTR / 256, 256, 0, stream>>>(g2bl, g2br, bcat2, HID);

  // --- CSR build (shared by both GAT layers) ---
  hipMemsetAsync(deg, 0, 131072, stream);  // deg + cursor (contiguous)
  build_edges_kernel<<<ET / 256, 256, 0, stream>>>(ei, srcA, dstA, deg);
  scan16k_kernel<<<1, 1024, 0, stream>>>(deg, rowstart);
  scatter_edges_kernel<<<ET / 256, 256, 0, stream>>>(srcA, dstA, rowstart, cursor, src_csr, dst_csr);

  // --- input projection + LN1 + gelu ---
  gemm_bf16_kernel<0, 0><<<(N_NODES / 256) * (HID / 128), 512, 0, stream>>>(
      xb, WinT, b_in, C, nullptr, N_NODES, HID, IN_DIM, HID / 128);
  ln_gelu_kernel<<<N_NODES, 256, 0, stream>>>(C, ln1g, ln1b, h, hb);

  // --- GAT layer 1 (fused xl|xr projection, N=2048) ---
  gemm_bf16_kernel<0, 2><<<(N_NODES / 256) * (XSTR / 128), 512, 0, stream>>>(
      hb, g1WT, bcat1, nullptr, xe, N_NODES, XSTR, HID, XSTR / 128);
  edge_logits_kernel<<<ET / 4, 256, 0, stream>>>(xe, g1att, src_csr, dst_csr, logits);
  gat_agg_ln_kernel<<<N_NODES, 256, 0, stream>>>(xe, logits, src_csr, rowstart, g1bo,
                                                 ln2g, ln2b, h, hb);

  // --- GAT layer 2 ---
  gemm_bf16_kernel<0, 2><<<(N_NODES / 256) * (XSTR / 128), 512, 0, stream>>>(
      hb, g2WT, bcat2, nullptr, xe, N_NODES, XSTR, HID, XSTR / 128);
  edge_logits_kernel<<<ET / 4, 256, 0, stream>>>(xe, g2att, src_csr, dst_csr, logits);
  gat_agg_ln_kernel<<<N_NODES, 256, 0, stream>>>(xe, logits, src_csr, rowstart, g2bo,
                                                 ln3g, ln3b, h, hb);

  // --- scorer MLP ---
  gemm_bf16_kernel<1, 2><<<(N_NODES / 256) * (512 / 128), 512, 0, stream>>>(
      hb, Ws1T, bs1, nullptr, s1b, N_NODES, 512, HID, 512 / 128);
  gemm_bf16_kernel<1, 0><<<(N_NODES / 256) * 1, 512, 0, stream>>>(
      s1b, Ws2T, bs2, C, nullptr, N_NODES, 128, 512, 1);
  score_kernel<<<N_NODES / 4, 256, 0, stream>>>(C, Ws3, bs3, scores);
}